// Round 5
// baseline (321.209 us; speedup 1.0000x reference)
//
#include <hip/hip_runtime.h>
#include <hip/hip_cooperative_groups.h>

namespace cg = cooperative_groups;

// B=8, MB=512, IN=1024, EMB=1024, H=16, KVH=4, HD=64, BS=16, K=32
// Single cooperative kernel, 512 WGs x 256 thr, phases P -> W -> GEMM -> softmax.
// GEMM 4096x1024x288 via split-bf16 MFMA: C = Ah*Bh + Ah*Bl + Al*Bh.

typedef __attribute__((ext_vector_type(8))) short v8s;
typedef __attribute__((ext_vector_type(4))) short v4sh;
typedef __attribute__((ext_vector_type(4))) float v4f;

// ws layout (floats)
#define OFF_WOR  0u          // [1024][2]
#define OFF_QR   2048u       // [16][1024]
#define OFF_WTH  18432u      // bf16 hi, transposed [320 j][1024 i]
#define OFF_WTL  182272u     // bf16 lo
#define OFF_S0   346112u     // [2048 rows][544]  row=((b*16+q)*16+h), data at [32..544)
#define OFF_S1   1460224u
#define OFF_VW0  2574336u    // [256 rows][544]   row=b*32+(h*2+c)
#define OFF_VW1  2713600u
#define SROW 544

__device__ __forceinline__ void split_bf16(float a, unsigned short& h, unsigned short& l) {
    const unsigned u = __float_as_uint(a);
    h = (unsigned short)(u >> 16);
    const float r = a - __uint_as_float(u & 0xFFFF0000u);   // exact residual
    unsigned v = __float_as_uint(r);
    v += 0x7FFFu + ((v >> 16) & 1u);                        // RNE to bf16
    l = (unsigned short)(v >> 16);
}

__global__ __launch_bounds__(256, 2) void fused(
    const float* __restrict__ A,                               // h [8][512][1024]
    const float* __restrict__ fc, const float* __restrict__ fs,
    const float* __restrict__ Wq, const float* __restrict__ Wk,
    const float* __restrict__ Wv, const float* __restrict__ Wo,
    const float* __restrict__ oq, const float* __restrict__ Wr,
    const float* __restrict__ brp,
    float* __restrict__ ws, float* __restrict__ out)
{
    __shared__ float smf[8192];   // 32 KB union across phases
    cg::grid_group grid = cg::this_grid();
    const int wg = blockIdx.x;    // [0,512)
    const int t = threadIdx.x;

    float* Wor = ws + OFF_WOR;
    float* qr  = ws + OFF_QR;
    unsigned short* Wth = (unsigned short*)(ws + OFF_WTH);
    unsigned short* Wtl = (unsigned short*)(ws + OFF_WTL);
    float* S0  = ws + OFF_S0;
    float* S1  = ws + OFF_S1;
    float* VW0 = ws + OFF_VW0;
    float* VW1 = ws + OFF_VW1;

    // ================= phase P: pads | qr (proj+RoPE) | Wor = Wo@Wr =================
    {
        // one zero-store per thread covers all pads
        const int gid = wg * 256 + t;
        if (gid < 36864) {
            const float4 z = make_float4(0.f, 0.f, 0.f, 0.f);
            if (gid < 16384)       *(float4*)(S0  + (size_t)(gid >> 3) * SROW + (gid & 7) * 4) = z;
            else if (gid < 32768)  *(float4*)(S1  + (size_t)((gid - 16384) >> 3) * SROW + (gid & 7) * 4) = z;
            else if (gid < 34816)  *(float4*)(VW0 + (size_t)((gid - 32768) >> 3) * SROW + (gid & 7) * 4) = z;
            else                   *(float4*)(VW1 + (size_t)((gid - 34816) >> 3) * SROW + (gid & 7) * 4) = z;
        } else if (gid < 45056) {
            const int j = gid - 36864;
            unsigned* dst = (unsigned*)((j < 4096) ? Wth : Wtl);
            const int jj = j & 4095;
            const uint4 z4 = make_uint4(0u, 0u, 0u, 0u);
            *(uint4*)(dst + 147456 + jj * 4) = z4;    // zero Wt pad rows 288..319
        }
        if (wg < 256) {
            // one (q, head): 64 output cols of qr; e-split across 4 waves
            const int q = wg >> 4, h = wg & 15;
            #pragma unroll
            for (int j = 0; j < 4; ++j) smf[t + 256 * j] = oq[q * 1024 + t + 256 * j];
            __syncthreads();
            const int w = t >> 6, lane = t & 63;
            const float* wq = Wq + (size_t)(w * 256) * 1024 + h * 64 + lane;
            const float* os = smf + w * 256;
            float acc = 0.f;
            #pragma unroll 8
            for (int e = 0; e < 256; ++e) acc = fmaf(os[e], wq[(size_t)e * 1024], acc);
            smf[1024 + w * 64 + lane] = acc;
            __syncthreads();
            if (t < 64) {
                const int d = t, p = d ^ 32;
                const float a1 = smf[1024 + d] + smf[1088 + d] + smf[1152 + d] + smf[1216 + d];
                const float a2 = smf[1024 + p] + smf[1088 + p] + smf[1152 + p] + smf[1216 + p];
                const float c = fc[q * 64 + d], s = fs[q * 64 + d];
                const float rh = (d < 32) ? -a2 : a2;
                qr[q * 1024 + h * 64 + d] = fmaf(a1, c, rh * s);
            }
        } else {
            // Wor = Wo @ Wr  (4 rows/WG, wave per row)
            #pragma unroll
            for (int j = 0; j < 8; ++j) smf[t + 256 * j] = Wr[t + 256 * j];
            __syncthreads();
            const int i = (wg - 256) * 4 + (t >> 6);
            const int lane = t & 63;
            float a0 = 0.f, a1 = 0.f;
            const float* wo = Wo + (size_t)i * 1024 + lane;
            #pragma unroll
            for (int j = 0; j < 16; ++j) {
                const float w = wo[j * 64];
                const int e = lane + j * 64;
                a0 = fmaf(w, smf[2 * e], a0);
                a1 = fmaf(w, smf[2 * e + 1], a1);
            }
            #pragma unroll
            for (int w = 1; w < 64; w <<= 1) {
                a0 += __shfl_xor(a0, w, 64);
                a1 += __shfl_xor(a1, w, 64);
            }
            if (lane == 0) { Wor[i * 2] = a0; Wor[i * 2 + 1] = a1; }
        }
    }
    grid.sync();

    // ================= phase W: folded weights -> Wth/Wtl bf16 [j][i] =================
    if (wg < 256) {
        const int g = wg & 3;               // kv-group
        const int i0 = (wg >> 2) * 16;      // 16-row chunk
        float* As = smf;                    // [16][68]
        float* Bt = smf + 1088;             // [72][68]  (qr cols | v cols)
        #pragma unroll
        for (int jj = 0; jj < 16; ++jj) {
            const int i2 = t + 256 * jj;    // < 4096
            const int d = i2 & 63, col = i2 >> 6;
            Bt[col * 68 + d] = qr[(col >> 2) * 1024 + (g * 4 + (col & 3)) * 64 + d];
        }
        #pragma unroll
        for (int jj = 0; jj < 2; ++jj) {
            const int i2 = t + 256 * jj;    // < 512
            const int d = i2 & 63, vc = i2 >> 6;
            Bt[(64 + vc) * 68 + d] = Wor[((g * 4 + (vc >> 1)) * 64 + d) * 2 + (vc & 1)];
        }
        {
            const int i = t >> 4, dc = (t & 15) * 4;
            *(float4*)&As[i * 68 + dc] = *(const float4*)(Wk + (size_t)(i0 + i) * 256 + g * 64 + dc);
        }
        __syncthreads();
        const int jc = t & 63, iq = t >> 6;
        {
            float o4[4] = {0.f, 0.f, 0.f, 0.f};
            #pragma unroll
            for (int dc = 0; dc < 16; ++dc) {
                const float4 bv = *(const float4*)&Bt[jc * 68 + dc * 4];
                #pragma unroll
                for (int r = 0; r < 4; ++r) {
                    const float4 av = *(const float4*)&As[(iq * 4 + r) * 68 + dc * 4];
                    o4[r] = fmaf(av.x, bv.x, o4[r]);
                    o4[r] = fmaf(av.y, bv.y, o4[r]);
                    o4[r] = fmaf(av.z, bv.z, o4[r]);
                    o4[r] = fmaf(av.w, bv.w, o4[r]);
                }
            }
            const int j = (jc >> 2) * 16 + g * 4 + (jc & 3);
            v4sh ph, pl;
            #pragma unroll
            for (int r = 0; r < 4; ++r) {
                unsigned short hh, ll;
                split_bf16(o4[r] * 0.125f, hh, ll);   // 1/sqrt(HD) folded in
                ph[r] = (short)hh; pl[r] = (short)ll;
            }
            *(v4sh*)&Wth[(size_t)j * 1024 + i0 + iq * 4] = ph;
            *(v4sh*)&Wtl[(size_t)j * 1024 + i0 + iq * 4] = pl;
        }
        __syncthreads();
        {
            const int i = t >> 4, dc = (t & 15) * 4;
            *(float4*)&As[i * 68 + dc] = *(const float4*)(Wv + (size_t)(i0 + i) * 256 + g * 64 + dc);
        }
        __syncthreads();
        if (t < 128) {
            const int il = t >> 3, vc = t & 7;
            float acc = 0.f;
            #pragma unroll
            for (int dc = 0; dc < 16; ++dc) {
                const float4 av = *(const float4*)&As[il * 68 + dc * 4];
                const float4 bv = *(const float4*)&Bt[(64 + vc) * 68 + dc * 4];
                acc = fmaf(av.x, bv.x, acc);
                acc = fmaf(av.y, bv.y, acc);
                acc = fmaf(av.z, bv.z, acc);
                acc = fmaf(av.w, bv.w, acc);
            }
            const int j = 256 + (g * 4 + (vc >> 1)) * 2 + (vc & 1);
            unsigned short hh, ll;
            split_bf16(acc, hh, ll);
            Wth[(size_t)j * 1024 + i0 + il] = hh;
            Wtl[(size_t)j * 1024 + i0 + il] = ll;
        }
    }
    grid.sync();

    // ================= phase G: split-bf16 MFMA GEMM, 640 tiles over 512 WGs ========
    {
        unsigned short* Ah = (unsigned short*)smf;   // [64][40]
        unsigned short* Al = Ah + 2560;
        unsigned short* Bh = Ah + 5120;
        unsigned short* Bl = Ah + 7680;
        const int lane = t & 63, wv = t >> 6;
        const int l16 = lane & 15, quad = lane >> 4;
        const int wm = wv >> 1, wn = wv & 1;
        const int sr = t >> 2, kc = (t & 3) * 8;
        for (int tile = wg; tile < 640; tile += 512) {
            const int kh = (tile >= 320) ? 1 : 0;
            const int r = tile - kh * 320;
            const int m0 = (r & 63) * 64;
            const int n0 = (r >> 6) * 64;
            v4f acc[2][2];
            #pragma unroll
            for (int i = 0; i < 2; ++i)
                #pragma unroll
                for (int j = 0; j < 2; ++j) acc[i][j] = (v4f)(0.f);
            const float* Ap = A + (size_t)(m0 + sr) * 1024 + kh * 512 + kc;
            const unsigned short* Bph = Wth + (size_t)(n0 + sr) * 1024 + kh * 512 + kc;
            const unsigned short* Bpl = Wtl + (size_t)(n0 + sr) * 1024 + kh * 512 + kc;
            for (int k0 = 0; k0 < 512; k0 += 32) {
                const float4 a0 = *(const float4*)(Ap + k0);
                const float4 a1 = *(const float4*)(Ap + k0 + 4);
                const v8s bhv = *(const v8s*)(Bph + k0);
                const v8s blv = *(const v8s*)(Bpl + k0);
                v8s ahv, alv;
                {
                    const float af[8] = {a0.x, a0.y, a0.z, a0.w, a1.x, a1.y, a1.z, a1.w};
                    #pragma unroll
                    for (int j = 0; j < 8; ++j) {
                        unsigned short hh, ll;
                        split_bf16(af[j], hh, ll);
                        ahv[j] = (short)hh; alv[j] = (short)ll;
                    }
                }
                __syncthreads();
                *(v8s*)&Ah[sr * 40 + kc] = ahv;
                *(v8s*)&Al[sr * 40 + kc] = alv;
                *(v8s*)&Bh[sr * 40 + kc] = bhv;
                *(v8s*)&Bl[sr * 40 + kc] = blv;
                __syncthreads();
                v8s fah[2], fal[2], fbh[2], fbl[2];
                #pragma unroll
                for (int s = 0; s < 2; ++s) {
                    const int mr = wm * 32 + s * 16 + l16;
                    fah[s] = *(const v8s*)&Ah[mr * 40 + quad * 8];
                    fal[s] = *(const v8s*)&Al[mr * 40 + quad * 8];
                    const int nr = wn * 32 + s * 16 + l16;
                    fbh[s] = *(const v8s*)&Bh[nr * 40 + quad * 8];
                    fbl[s] = *(const v8s*)&Bl[nr * 40 + quad * 8];
                }
                #pragma unroll
                for (int ms = 0; ms < 2; ++ms)
                    #pragma unroll
                    for (int ns = 0; ns < 2; ++ns) {
                        acc[ms][ns] = __builtin_amdgcn_mfma_f32_16x16x32_bf16(fal[ms], fbh[ns], acc[ms][ns], 0, 0, 0);
                        acc[ms][ns] = __builtin_amdgcn_mfma_f32_16x16x32_bf16(fah[ms], fbl[ns], acc[ms][ns], 0, 0, 0);
                        acc[ms][ns] = __builtin_amdgcn_mfma_f32_16x16x32_bf16(fah[ms], fbh[ns], acc[ms][ns], 0, 0, 0);
                    }
            }
            float* Sh  = kh ? S1 : S0;
            float* VWh = kh ? VW1 : VW0;
            #pragma unroll
            for (int ms = 0; ms < 2; ++ms)
                #pragma unroll
                for (int ns = 0; ns < 2; ++ns) {
                    const int j = n0 + wn * 32 + ns * 16 + l16;
                    if (j >= 288) continue;
                    const int m = m0 + wm * 32 + ms * 16 + quad * 4;   // C/D: col=lane&15, row=quad*4+reg
                    const int bb = m >> 9, tt = m & 511;
                    const float4 v = make_float4(acc[ms][ns][0], acc[ms][ns][1], acc[ms][ns][2], acc[ms][ns][3]);
                    float* dst;
                    if (j < 256)
                        dst = Sh + (size_t)((bb * 16 + (j >> 4)) * 16 + (j & 15)) * SROW + 32 + tt;
                    else
                        dst = VWh + (size_t)(bb * 32 + (j - 256)) * SROW + 32 + tt;
                    *(float4*)dst = v;
                }
        }
    }
    grid.sync();

    // ================= phase S: exp + sliding-window softmax + head-reduce ==========
    {
        float* Es  = smf;            // [16][164]
        float* EVs = smf + 2624;     // [32][164]
        const int b = wg >> 6, q = (wg >> 2) & 15, qt = wg & 3;
        const int tbase = qt * 128;  // 128 m-values per WG
        for (int idx = t; idx < 640; idx += 256) {          // 16 h x 40 float4 (wi<160)
            const int h = idx / 40, g = idx - h * 40;
            const size_t off = (size_t)((b * 16 + q) * 16 + h) * SROW + tbase + g * 4;
            const float4 a = *(const float4*)(S0 + off);
            const float4 c = *(const float4*)(S1 + off);
            float4 e;
            e.x = __expf(a.x + c.x); e.y = __expf(a.y + c.y);
            e.z = __expf(a.z + c.z); e.w = __expf(a.w + c.w);
            *(float4*)(Es + h * 164 + g * 4) = e;
        }
        __syncthreads();
        for (int idx = t; idx < 1280; idx += 256) {         // 32 hc x 40 float4
            const int hc = idx / 40, g = idx - hc * 40;
            const size_t off = (size_t)(b * 32 + hc) * SROW + tbase + g * 4;
            const float4 v0 = *(const float4*)(VW0 + off);
            const float4 v1 = *(const float4*)(VW1 + off);
            const float4 e = *(const float4*)(Es + (hc >> 1) * 164 + g * 4);
            float4 rr;
            rr.x = e.x * (v0.x + v1.x); rr.y = e.y * (v0.y + v1.y);
            rr.z = e.z * (v0.z + v1.z); rr.w = e.w * (v0.w + v1.w);
            *(float4*)(EVs + hc * 164 + g * 4) = rr;
        }
        __syncthreads();
        const int h = t & 15, mg = t >> 4;
        const float* ep = Es + h * 164 + mg * 8;
        const float* e0 = EVs + (2 * h) * 164 + mg * 8;
        const float* e1 = EVs + (2 * h + 1) * 164 + mg * 8;
        float den = 0.f, n0s = 0.f, n1s = 0.f;
        #pragma unroll
        for (int s = 0; s < 32; ++s) {
            const int ss = 1 + ((s + 2 * h) & 31);          // bank-rotated
            den += ep[ss]; n0s += e0[ss]; n1s += e1[ss];
        }
        const float br0 = brp[0], br1 = brp[1];
        for (int u = 0; u < 8; ++u) {
            const float inv = 1.f / den;
            float c0 = n0s * inv, c1 = n1s * inv;
            #pragma unroll
            for (int w = 1; w < 16; w <<= 1) {
                c0 += __shfl_xor(c0, w, 64);
                c1 += __shfl_xor(c1, w, 64);
            }
            if (h == 0) {
                const int m = tbase + mg * 8 + u;
                float* o = out + (size_t)((b * 512 + m) * 16 + q) * 2;
                o[0] = c0 + br0;
                o[1] = c1 + br1;
            }
            if (u < 7) {
                den += ep[33 + u] - ep[1 + u];
                n0s += e0[33 + u] - e0[1 + u];
                n1s += e1[33 + u] - e1[1 + u];
            }
        }
    }
}

extern "C" void kernel_launch(void* const* d_in, const int* in_sizes, int n_in,
                              void* d_out, int out_size, void* d_ws, size_t ws_size,
                              hipStream_t stream)
{
    (void)in_sizes; (void)n_in; (void)out_size; (void)ws_size;
    const float* h  = (const float*)d_in[0];
    const float* fc = (const float*)d_in[1];
    const float* fs = (const float*)d_in[2];
    const float* Wq = (const float*)d_in[3];
    const float* Wk = (const float*)d_in[4];
    const float* Wv = (const float*)d_in[5];
    const float* Wo = (const float*)d_in[6];
    const float* oq = (const float*)d_in[7];
    const float* Wr = (const float*)d_in[8];
    const float* br = (const float*)d_in[9];
    float* ws = (float*)d_ws;
    float* out = (float*)d_out;

    void* args[] = {
        (void*)&h, (void*)&fc, (void*)&fs, (void*)&Wq, (void*)&Wk, (void*)&Wv,
        (void*)&Wo, (void*)&oq, (void*)&Wr, (void*)&br, (void*)&ws, (void*)&out
    };
    hipLaunchCooperativeKernel((const void*)fused, dim3(512), dim3(256), args, 0, stream);
}

// Round 6
// 123.479 us; speedup vs baseline: 2.6013x; 2.6013x over previous
//
#include <hip/hip_runtime.h>

// B=8, MB=512, IN=1024, EMB=1024, H=16, KVH=4, HD=64, BS=16, K=32
//
// S[b,t,h,q]  = h[b,t] . (Wk_head @ qr[q,h,:]) / 8
// VW[b,t,h,c] = h[b,t] . (Wv_head @ (Wo@Wr)[h*64:(h+1)*64, c])
// vel[b,m,q,c] = br[c] + sum_h [win-sum E*VW] / [win-sum E],  E=exp(S)
// GEMM 4096x1024x288 via split-bf16 MFMA: C = Ah*Bh + Ah*Bl + Al*Bh.
// 4 plain launches (cooperative grid.sync measured ~70us/sync on 8 XCDs — rejected).

typedef __attribute__((ext_vector_type(8))) short v8s;
typedef __attribute__((ext_vector_type(4))) short v4sh;
typedef __attribute__((ext_vector_type(4))) float v4f;

// ws layout (floats)
#define OFF_WOR  0u          // [1024][2]
#define OFF_QR   2048u       // [16][1024]
#define OFF_WTH  18432u      // bf16 hi, transposed [320 j][1024 i]
#define OFF_WTL  182272u     // bf16 lo
#define OFF_S0   346112u     // [2048 rows][544]  row=((b*16+q)*16+h), data at [32..544)
#define OFF_S1   1460224u
#define OFF_VW0  2574336u    // [256 rows][544]   row=b*32+(h*2+c)
#define OFF_VW1  2713600u
#define SROW 544

__device__ __forceinline__ void split_bf16(float a, unsigned short& h, unsigned short& l) {
    const unsigned u = __float_as_uint(a);
    h = (unsigned short)(u >> 16);
    const float r = a - __uint_as_float(u & 0xFFFF0000u);   // exact residual
    unsigned v = __float_as_uint(r);
    v += 0x7FFFu + ((v >> 16) & 1u);                        // RNE to bf16
    l = (unsigned short)(v >> 16);
}

// ---------------- kP: qr (proj+RoPE) | Wor = Wo@Wr | zero pads ----------------
__global__ __launch_bounds__(256) void kP(
    const float* __restrict__ oq, const float* __restrict__ Wq,
    const float* __restrict__ fc, const float* __restrict__ fs,
    const float* __restrict__ Wo, const float* __restrict__ Wr,
    float* __restrict__ qr, float* __restrict__ Wor,
    float* __restrict__ S0, float* __restrict__ S1,
    float* __restrict__ VW0, float* __restrict__ VW1,
    unsigned* __restrict__ wthu, unsigned* __restrict__ wtlu)
{
    __shared__ float sm[2048];
    const int b = blockIdx.x, t = threadIdx.x;
    if (b < 256) {
        // one (q, head) pair: 64 output cols; e-split across 4 waves
        const int q = b >> 4, h = b & 15;
        #pragma unroll
        for (int j = 0; j < 4; ++j) sm[t + 256 * j] = oq[q * 1024 + t + 256 * j];
        __syncthreads();
        const int w = t >> 6, lane = t & 63;
        const float* wq = Wq + (size_t)(w * 256) * 1024 + h * 64 + lane;
        const float* os = sm + w * 256;
        float acc = 0.f;
        #pragma unroll 16
        for (int e = 0; e < 256; ++e) acc = fmaf(os[e], wq[(size_t)e * 1024], acc);
        sm[1024 + w * 64 + lane] = acc;
        __syncthreads();
        if (t < 64) {
            const int d = t, p = d ^ 32;
            const float a1 = sm[1024 + d] + sm[1088 + d] + sm[1152 + d] + sm[1216 + d];
            const float a2 = sm[1024 + p] + sm[1088 + p] + sm[1152 + p] + sm[1216 + p];
            const float c = fc[q * 64 + d], s = fs[q * 64 + d];
            const float rh = (d < 32) ? -a2 : a2;
            qr[q * 1024 + h * 64 + d] = fmaf(a1, c, rh * s);
        }
    } else if (b < 512) {
        // Wor = Wo @ Wr  (4 rows/block, wave per row)
        #pragma unroll
        for (int j = 0; j < 8; ++j) sm[t + 256 * j] = Wr[t + 256 * j];
        __syncthreads();
        const int i = (b - 256) * 4 + (t >> 6);
        const int lane = t & 63;
        float a0 = 0.f, a1 = 0.f;
        const float* wo = Wo + (size_t)i * 1024 + lane;
        #pragma unroll
        for (int j = 0; j < 16; ++j) {
            const float w = wo[j * 64];
            const int e = lane + j * 64;
            a0 = fmaf(w, sm[2 * e], a0);
            a1 = fmaf(w, sm[2 * e + 1], a1);
        }
        #pragma unroll
        for (int w = 1; w < 64; w <<= 1) {
            a0 += __shfl_xor(a0, w, 64);
            a1 += __shfl_xor(a1, w, 64);
        }
        if (lane == 0) { Wor[i * 2] = a0; Wor[i * 2 + 1] = a1; }
    } else if (b < 656) {
        // zero left-pads (32 floats = 8 float4 per row)
        const int idx = (b - 512) * 256 + t;  // < 36864
        const float4 z = make_float4(0.f, 0.f, 0.f, 0.f);
        if (idx < 16384)       *(float4*)(S0  + (size_t)(idx >> 3) * SROW + (idx & 7) * 4) = z;
        else if (idx < 32768)  *(float4*)(S1  + (size_t)((idx - 16384) >> 3) * SROW + (idx & 7) * 4) = z;
        else if (idx < 34816)  *(float4*)(VW0 + (size_t)((idx - 32768) >> 3) * SROW + (idx & 7) * 4) = z;
        else                   *(float4*)(VW1 + (size_t)((idx - 34816) >> 3) * SROW + (idx & 7) * 4) = z;
    } else {
        // zero Wt pad rows 288..319 (16384 u32 per array)
        unsigned* dst = (b == 656) ? wthu : wtlu;
        #pragma unroll
        for (int j = 0; j < 64; ++j) dst[147456 + t + 256 * j] = 0u;
    }
}

// ---------------- kW: folded weights -> Wth/Wtl bf16 transposed [j][i] ----------------
// per kv-group g: (32i x 64d Wk|Wv) @ (64d x 72jc [qr-cols | v-cols])
__global__ __launch_bounds__(256) void kW(
    const float* __restrict__ Wk, const float* __restrict__ Wv,
    const float* __restrict__ qr, const float* __restrict__ Wor,
    unsigned short* __restrict__ Wth, unsigned short* __restrict__ Wtl)
{
    __shared__ float As[32 * 68];
    __shared__ float Bt[72 * 68];   // [jc][d]
    const int b = blockIdx.x, t = threadIdx.x;
    const int g = b >> 5, i0 = (b & 31) * 32;
    #pragma unroll
    for (int jj = 0; jj < 16; ++jj) {
        const int i2 = t + 256 * jj;
        const int d = i2 & 63, col = i2 >> 6;
        Bt[col * 68 + d] = qr[(col >> 2) * 1024 + (g * 4 + (col & 3)) * 64 + d];
    }
    #pragma unroll
    for (int jj = 0; jj < 2; ++jj) {
        const int i2 = t + 256 * jj;
        const int d = i2 & 63, vc = i2 >> 6;
        Bt[(64 + vc) * 68 + d] = Wor[((g * 4 + (vc >> 1)) * 64 + d) * 2 + (vc & 1)];
    }
    {
        const int i = t >> 3, dc = (t & 7) * 8;
        const float* src = Wk + (size_t)(i0 + i) * 256 + g * 64 + dc;
        *(float4*)&As[i * 68 + dc] = *(const float4*)src;
        *(float4*)&As[i * 68 + dc + 4] = *(const float4*)(src + 4);
    }
    __syncthreads();
    const int jc = t & 63, iq = t >> 6;
    {
        float out[8];
        #pragma unroll
        for (int r = 0; r < 8; ++r) out[r] = 0.f;
        #pragma unroll
        for (int dc = 0; dc < 16; ++dc) {
            const float4 bv = *(const float4*)&Bt[jc * 68 + dc * 4];
            #pragma unroll
            for (int r = 0; r < 8; ++r) {
                const float4 av = *(const float4*)&As[(iq * 8 + r) * 68 + dc * 4];
                out[r] = fmaf(av.x, bv.x, out[r]);
                out[r] = fmaf(av.y, bv.y, out[r]);
                out[r] = fmaf(av.z, bv.z, out[r]);
                out[r] = fmaf(av.w, bv.w, out[r]);
            }
        }
        const int j = (jc >> 2) * 16 + g * 4 + (jc & 3);
        v8s ph, pl;
        #pragma unroll
        for (int r = 0; r < 8; ++r) {
            unsigned short hh, ll;
            split_bf16(out[r] * 0.125f, hh, ll);   // 1/sqrt(HD) folded in
            ph[r] = (short)hh; pl[r] = (short)ll;
        }
        *(v8s*)&Wth[(size_t)j * 1024 + i0 + iq * 8] = ph;
        *(v8s*)&Wtl[(size_t)j * 1024 + i0 + iq * 8] = pl;
    }
    __syncthreads();
    {
        const int i = t >> 3, dc = (t & 7) * 8;
        const float* src = Wv + (size_t)(i0 + i) * 256 + g * 64 + dc;
        *(float4*)&As[i * 68 + dc] = *(const float4*)src;
        *(float4*)&As[i * 68 + dc + 4] = *(const float4*)(src + 4);
    }
    __syncthreads();
    {
        const int il = t >> 3, vc = t & 7;
        float acc = 0.f;
        #pragma unroll
        for (int dc = 0; dc < 16; ++dc) {
            const float4 av = *(const float4*)&As[il * 68 + dc * 4];
            const float4 bv = *(const float4*)&Bt[(64 + vc) * 68 + dc * 4];
            acc = fmaf(av.x, bv.x, acc);
            acc = fmaf(av.y, bv.y, acc);
            acc = fmaf(av.z, bv.z, acc);
            acc = fmaf(av.w, bv.w, acc);
        }
        const int j = 256 + (g * 4 + (vc >> 1)) * 2 + (vc & 1);
        unsigned short hh, ll;
        split_bf16(acc, hh, ll);
        Wth[(size_t)j * 1024 + i0 + il] = hh;
        Wtl[(size_t)j * 1024 + i0 + il] = ll;
    }
}

// ---------------- k2: split-bf16 MFMA GEMM, tile 64x64, BK=64, K-split 2 ----------------
__global__ __launch_bounds__(256) void k2(
    const float* __restrict__ A,
    const unsigned short* __restrict__ Wth, const unsigned short* __restrict__ Wtl,
    float* __restrict__ S0, float* __restrict__ S1,
    float* __restrict__ VW0, float* __restrict__ VW1)
{
    __shared__ unsigned short Ah[64 * 72], Al[64 * 72];   // [m][k], stride 72 shorts
    __shared__ unsigned short Bh[64 * 72], Bl[64 * 72];   // [n][k]   (36 KB total)
    const int m0 = blockIdx.x * 64;
    const int n0 = blockIdx.y * 64;
    const int kh = blockIdx.z;
    const int t = threadIdx.x;
    const int lane = t & 63, wv = t >> 6;
    const int l16 = lane & 15, quad = lane >> 4;
    const int wm = wv >> 1, wn = wv & 1;
    const int sr = t >> 2, kc = (t & 3) * 8;
    v4f acc[2][2];
    #pragma unroll
    for (int i = 0; i < 2; ++i)
        #pragma unroll
        for (int j = 0; j < 2; ++j) acc[i][j] = (v4f)(0.f);
    const float* Ap = A + (size_t)(m0 + sr) * 1024 + kh * 512 + kc;
    const unsigned short* Bph = Wth + (size_t)(n0 + sr) * 1024 + kh * 512 + kc;
    const unsigned short* Bpl = Wtl + (size_t)(n0 + sr) * 1024 + kh * 512 + kc;
    for (int k0 = 0; k0 < 512; k0 += 64) {
        const float4 a00 = *(const float4*)(Ap + k0);
        const float4 a01 = *(const float4*)(Ap + k0 + 4);
        const float4 a10 = *(const float4*)(Ap + k0 + 32);
        const float4 a11 = *(const float4*)(Ap + k0 + 36);
        const v8s bh0 = *(const v8s*)(Bph + k0);
        const v8s bh1 = *(const v8s*)(Bph + k0 + 32);
        const v8s bl0 = *(const v8s*)(Bpl + k0);
        const v8s bl1 = *(const v8s*)(Bpl + k0 + 32);
        v8s ah0, al0, ah1, al1;
        {
            const float af0[8] = {a00.x, a00.y, a00.z, a00.w, a01.x, a01.y, a01.z, a01.w};
            const float af1[8] = {a10.x, a10.y, a10.z, a10.w, a11.x, a11.y, a11.z, a11.w};
            #pragma unroll
            for (int j = 0; j < 8; ++j) {
                unsigned short hh, ll;
                split_bf16(af0[j], hh, ll);
                ah0[j] = (short)hh; al0[j] = (short)ll;
                split_bf16(af1[j], hh, ll);
                ah1[j] = (short)hh; al1[j] = (short)ll;
            }
        }
        __syncthreads();
        *(v8s*)&Ah[sr * 72 + kc] = ah0;  *(v8s*)&Ah[sr * 72 + kc + 32] = ah1;
        *(v8s*)&Al[sr * 72 + kc] = al0;  *(v8s*)&Al[sr * 72 + kc + 32] = al1;
        *(v8s*)&Bh[sr * 72 + kc] = bh0;  *(v8s*)&Bh[sr * 72 + kc + 32] = bh1;
        *(v8s*)&Bl[sr * 72 + kc] = bl0;  *(v8s*)&Bl[sr * 72 + kc + 32] = bl1;
        __syncthreads();
        #pragma unroll
        for (int kk = 0; kk < 2; ++kk) {
            v8s fah[2], fal[2], fbh[2], fbl[2];
            #pragma unroll
            for (int s = 0; s < 2; ++s) {
                const int mr = wm * 32 + s * 16 + l16;
                fah[s] = *(const v8s*)&Ah[mr * 72 + kk * 32 + quad * 8];
                fal[s] = *(const v8s*)&Al[mr * 72 + kk * 32 + quad * 8];
                const int nr = wn * 32 + s * 16 + l16;
                fbh[s] = *(const v8s*)&Bh[nr * 72 + kk * 32 + quad * 8];
                fbl[s] = *(const v8s*)&Bl[nr * 72 + kk * 32 + quad * 8];
            }
            #pragma unroll
            for (int ms = 0; ms < 2; ++ms)
                #pragma unroll
                for (int ns = 0; ns < 2; ++ns) {
                    acc[ms][ns] = __builtin_amdgcn_mfma_f32_16x16x32_bf16(fal[ms], fbh[ns], acc[ms][ns], 0, 0, 0);
                    acc[ms][ns] = __builtin_amdgcn_mfma_f32_16x16x32_bf16(fah[ms], fbl[ns], acc[ms][ns], 0, 0, 0);
                    acc[ms][ns] = __builtin_amdgcn_mfma_f32_16x16x32_bf16(fah[ms], fbh[ns], acc[ms][ns], 0, 0, 0);
                }
        }
    }
    float* Sh  = kh ? S1 : S0;
    float* VWh = kh ? VW1 : VW0;
    #pragma unroll
    for (int ms = 0; ms < 2; ++ms)
        #pragma unroll
        for (int ns = 0; ns < 2; ++ns) {
            const int j = n0 + wn * 32 + ns * 16 + l16;
            if (j >= 288) continue;
            const int m = m0 + wm * 32 + ms * 16 + quad * 4;   // C/D: col=lane&15, row=quad*4+reg
            const int bb = m >> 9, tt = m & 511;
            const float4 v = make_float4(acc[ms][ns][0], acc[ms][ns][1], acc[ms][ns][2], acc[ms][ns][3]);
            float* dst;
            if (j < 256)
                dst = Sh + (size_t)((bb * 16 + (j >> 4)) * 16 + (j & 15)) * SROW + 32 + tt;
            else
                dst = VWh + (size_t)(bb * 32 + (j - 256)) * SROW + 32 + tt;
            *(float4*)dst = v;
        }
}

// ---------------- k3: exp + sliding-window softmax + head-reduce (quarter-m) -------
__global__ __launch_bounds__(256) void k3(
    const float* __restrict__ S0, const float* __restrict__ S1,
    const float* __restrict__ VW0, const float* __restrict__ VW1,
    const float* __restrict__ brp, float* __restrict__ out)
{
    __shared__ float Es[16 * 164];
    __shared__ float EVs[32 * 164];
    const int b = blockIdx.x, q = blockIdx.y, qt = blockIdx.z;
    const int tbase = qt * 128;
    const int t = threadIdx.x;
    for (int idx = t; idx < 640; idx += 256) {          // 16 h x 40 float4 (wi<160)
        const int h = idx / 40, g = idx - h * 40;
        const size_t off = (size_t)((b * 16 + q) * 16 + h) * SROW + tbase + g * 4;
        const float4 a = *(const float4*)(S0 + off);
        const float4 c = *(const float4*)(S1 + off);
        float4 e;
        e.x = __expf(a.x + c.x); e.y = __expf(a.y + c.y);
        e.z = __expf(a.z + c.z); e.w = __expf(a.w + c.w);
        *(float4*)(Es + h * 164 + g * 4) = e;
    }
    __syncthreads();
    for (int idx = t; idx < 1280; idx += 256) {         // 32 hc x 40 float4
        const int hc = idx / 40, g = idx - hc * 40;
        const size_t off = (size_t)(b * 32 + hc) * SROW + tbase + g * 4;
        const float4 v0 = *(const float4*)(VW0 + off);
        const float4 v1 = *(const float4*)(VW1 + off);
        const float4 e = *(const float4*)(Es + (hc >> 1) * 164 + g * 4);
        float4 rr;
        rr.x = e.x * (v0.x + v1.x); rr.y = e.y * (v0.y + v1.y);
        rr.z = e.z * (v0.z + v1.z); rr.w = e.w * (v0.w + v1.w);
        *(float4*)(EVs + hc * 164 + g * 4) = rr;
    }
    __syncthreads();
    const int h = t & 15, mg = t >> 4;
    const float* ep = Es + h * 164 + mg * 8;
    const float* e0 = EVs + (2 * h) * 164 + mg * 8;
    const float* e1 = EVs + (2 * h + 1) * 164 + mg * 8;
    float den = 0.f, n0s = 0.f, n1s = 0.f;
    #pragma unroll
    for (int s = 0; s < 32; ++s) {
        const int ss = 1 + ((s + 2 * h) & 31);          // bank-rotated
        den += ep[ss]; n0s += e0[ss]; n1s += e1[ss];
    }
    const float br0 = brp[0], br1 = brp[1];
    #pragma unroll
    for (int u = 0; u < 8; ++u) {
        const float inv = __builtin_amdgcn_rcpf(den);
        float c0 = n0s * inv, c1 = n1s * inv;
        #pragma unroll
        for (int w = 1; w < 16; w <<= 1) {
            c0 += __shfl_xor(c0, w, 64);
            c1 += __shfl_xor(c1, w, 64);
        }
        if (h == 0) {
            const int m = tbase + mg * 8 + u;
            float* o = out + (size_t)((b * 512 + m) * 16 + q) * 2;
            o[0] = c0 + br0;
            o[1] = c1 + br1;
        }
        if (u < 7) {
            den += ep[33 + u] - ep[1 + u];
            n0s += e0[33 + u] - e0[1 + u];
            n1s += e1[33 + u] - e1[1 + u];
        }
    }
}

extern "C" void kernel_launch(void* const* d_in, const int* in_sizes, int n_in,
                              void* d_out, int out_size, void* d_ws, size_t ws_size,
                              hipStream_t stream)
{
    (void)in_sizes; (void)n_in; (void)out_size; (void)ws_size;
    const float* h  = (const float*)d_in[0];
    const float* fc = (const float*)d_in[1];
    const float* fs = (const float*)d_in[2];
    const float* Wq = (const float*)d_in[3];
    const float* Wk = (const float*)d_in[4];
    const float* Wv = (const float*)d_in[5];
    const float* Wo = (const float*)d_in[6];
    const float* oq = (const float*)d_in[7];
    const float* Wr = (const float*)d_in[8];
    const float* br = (const float*)d_in[9];
    float* ws = (float*)d_ws;
    float* Wor  = ws + OFF_WOR;
    float* qr   = ws + OFF_QR;
    unsigned short* Wth = (unsigned short*)(ws + OFF_WTH);
    unsigned short* Wtl = (unsigned short*)(ws + OFF_WTL);
    float* S0   = ws + OFF_S0;
    float* S1   = ws + OFF_S1;
    float* VW0  = ws + OFF_VW0;
    float* VW1  = ws + OFF_VW1;
    float* out = (float*)d_out;

    hipLaunchKernelGGL(kP, dim3(658), dim3(256), 0, stream,
                       oq, Wq, fc, fs, Wo, Wr, qr, Wor, S0, S1, VW0, VW1,
                       (unsigned*)Wth, (unsigned*)Wtl);
    hipLaunchKernelGGL(kW, dim3(128), dim3(256), 0, stream, Wk, Wv, qr, Wor, Wth, Wtl);
    hipLaunchKernelGGL(k2, dim3(64, 5, 2), dim3(256), 0, stream, h, Wth, Wtl, S0, S1, VW0, VW1);
    hipLaunchKernelGGL(k3, dim3(8, 16, 4), dim3(256), 0, stream, S0, S1, VW0, VW1, br, out);
}

// Round 7
// 121.849 us; speedup vs baseline: 2.6361x; 1.0134x over previous
//
#include <hip/hip_runtime.h>

// B=8, MB=512, IN=1024, EMB=1024, H=16, KVH=4, HD=64, BS=16, K=32
//
// S[b,t,h,q]  = h[b,t] . (Wk_head @ qr[q,h,:]) / 8
// VW[b,t,h,c] = h[b,t] . (Wv_head @ (Wo@Wr)[h*64:(h+1)*64, c])
// vel[b,m,q,c] = br[c] + sum_h [win-sum E*VW] / [win-sum E],  E=exp(S)
// GEMM 4096x1024x288 via split-bf16 MFMA: C = Ah*Bh + Ah*Bl + Al*Bh.
// A's fp32->bf16hi/lo split is precomputed in kP (was ~450 wave-VALU/blk-iter
// inside k2's barrier pair). k2 K-loop: prefetch regs -> LDS -> MFMA.

typedef __attribute__((ext_vector_type(8))) short v8s;
typedef __attribute__((ext_vector_type(4))) float v4f;

// ws layout (floats)
#define OFF_WOR  0u          // [1024][2]
#define OFF_QR   2048u       // [16][1024]
#define OFF_WTH  18432u      // bf16 hi, transposed [320 j][1024 i]
#define OFF_WTL  182272u     // bf16 lo
#define OFF_S0   346112u     // [2048 rows][544]  row=((b*16+q)*16+h), data at [32..544)
#define OFF_S1   1460224u
#define OFF_VW0  2574336u    // [256 rows][544]   row=b*32+(h*2+c)
#define OFF_VW1  2713600u
#define OFF_AH   2852864u    // bf16 hi of h, [4096 m][1024 k]  (2097152 floats)
#define OFF_AL   4950016u    // bf16 lo
#define SROW 544

__device__ __forceinline__ void split_bf16(float a, unsigned short& h, unsigned short& l) {
    const unsigned u = __float_as_uint(a);
    h = (unsigned short)(u >> 16);
    const float r = a - __uint_as_float(u & 0xFFFF0000u);   // exact residual
    unsigned v = __float_as_uint(r);
    v += 0x7FFFu + ((v >> 16) & 1u);                        // RNE to bf16
    l = (unsigned short)(v >> 16);
}

// ---- kP: qr (proj+RoPE) | Wor = Wo@Wr | zero pads | h -> Ah/Al bf16 split ----
__global__ __launch_bounds__(256) void kP(
    const float* __restrict__ oq, const float* __restrict__ Wq,
    const float* __restrict__ fc, const float* __restrict__ fs,
    const float* __restrict__ Wo, const float* __restrict__ Wr,
    const float* __restrict__ hsrc,
    float* __restrict__ qr, float* __restrict__ Wor,
    float* __restrict__ S0, float* __restrict__ S1,
    float* __restrict__ VW0, float* __restrict__ VW1,
    unsigned* __restrict__ wthu, unsigned* __restrict__ wtlu,
    unsigned short* __restrict__ Ahg, unsigned short* __restrict__ Alg)
{
    __shared__ float sm[2048];
    const int b = blockIdx.x, t = threadIdx.x;
    if (b >= 658) {
        // split h into bf16 hi/lo: 2048 elems per block, 8 per thread
        const int base = (b - 658) * 2048 + t * 8;
        const float4 x0 = *(const float4*)(hsrc + base);
        const float4 x1 = *(const float4*)(hsrc + base + 4);
        const float af[8] = {x0.x, x0.y, x0.z, x0.w, x1.x, x1.y, x1.z, x1.w};
        v8s ah, al;
        #pragma unroll
        for (int j = 0; j < 8; ++j) {
            unsigned short hh, ll;
            split_bf16(af[j], hh, ll);
            ah[j] = (short)hh; al[j] = (short)ll;
        }
        *(v8s*)(Ahg + base) = ah;
        *(v8s*)(Alg + base) = al;
        return;
    }
    if (b < 256) {
        // one (q, head) pair: 64 output cols; e-split across 4 waves
        const int q = b >> 4, h = b & 15;
        #pragma unroll
        for (int j = 0; j < 4; ++j) sm[t + 256 * j] = oq[q * 1024 + t + 256 * j];
        __syncthreads();
        const int w = t >> 6, lane = t & 63;
        const float* wq = Wq + (size_t)(w * 256) * 1024 + h * 64 + lane;
        const float* os = sm + w * 256;
        float acc = 0.f;
        #pragma unroll 16
        for (int e = 0; e < 256; ++e) acc = fmaf(os[e], wq[(size_t)e * 1024], acc);
        sm[1024 + w * 64 + lane] = acc;
        __syncthreads();
        if (t < 64) {
            const int d = t, p = d ^ 32;
            const float a1 = sm[1024 + d] + sm[1088 + d] + sm[1152 + d] + sm[1216 + d];
            const float a2 = sm[1024 + p] + sm[1088 + p] + sm[1152 + p] + sm[1216 + p];
            const float c = fc[q * 64 + d], s = fs[q * 64 + d];
            const float rh = (d < 32) ? -a2 : a2;
            qr[q * 1024 + h * 64 + d] = fmaf(a1, c, rh * s);
        }
    } else if (b < 512) {
        // Wor = Wo @ Wr  (4 rows/block, wave per row)
        #pragma unroll
        for (int j = 0; j < 8; ++j) sm[t + 256 * j] = Wr[t + 256 * j];
        __syncthreads();
        const int i = (b - 256) * 4 + (t >> 6);
        const int lane = t & 63;
        float a0 = 0.f, a1 = 0.f;
        const float* wo = Wo + (size_t)i * 1024 + lane;
        #pragma unroll
        for (int j = 0; j < 16; ++j) {
            const float w = wo[j * 64];
            const int e = lane + j * 64;
            a0 = fmaf(w, sm[2 * e], a0);
            a1 = fmaf(w, sm[2 * e + 1], a1);
        }
        #pragma unroll
        for (int w = 1; w < 64; w <<= 1) {
            a0 += __shfl_xor(a0, w, 64);
            a1 += __shfl_xor(a1, w, 64);
        }
        if (lane == 0) { Wor[i * 2] = a0; Wor[i * 2 + 1] = a1; }
    } else if (b < 656) {
        // zero left-pads (32 floats = 8 float4 per row)
        const int idx = (b - 512) * 256 + t;  // < 36864
        const float4 z = make_float4(0.f, 0.f, 0.f, 0.f);
        if (idx < 16384)       *(float4*)(S0  + (size_t)(idx >> 3) * SROW + (idx & 7) * 4) = z;
        else if (idx < 32768)  *(float4*)(S1  + (size_t)((idx - 16384) >> 3) * SROW + (idx & 7) * 4) = z;
        else if (idx < 34816)  *(float4*)(VW0 + (size_t)((idx - 32768) >> 3) * SROW + (idx & 7) * 4) = z;
        else                   *(float4*)(VW1 + (size_t)((idx - 34816) >> 3) * SROW + (idx & 7) * 4) = z;
    } else {
        // zero Wt pad rows 288..319 (16384 u32 per array)
        unsigned* dst = (b == 656) ? wthu : wtlu;
        #pragma unroll
        for (int j = 0; j < 64; ++j) dst[147456 + t + 256 * j] = 0u;
    }
}

// ---------------- kW: folded weights -> Wth/Wtl bf16 transposed [j][i] ----------------
// per kv-group g, 16-row chunk: (16i x 64d Wk|Wv) @ (64d x 72jc)
__global__ __launch_bounds__(256) void kW(
    const float* __restrict__ Wk, const float* __restrict__ Wv,
    const float* __restrict__ qr, const float* __restrict__ Wor,
    unsigned short* __restrict__ Wth, unsigned short* __restrict__ Wtl)
{
    __shared__ float As[16 * 68];
    __shared__ float Bt[72 * 68];   // [jc][d]
    const int b = blockIdx.x, t = threadIdx.x;
    const int g = b & 3, i0 = (b >> 2) * 16;
    #pragma unroll
    for (int jj = 0; jj < 16; ++jj) {
        const int i2 = t + 256 * jj;    // < 4096
        const int d = i2 & 63, col = i2 >> 6;
        Bt[col * 68 + d] = qr[(col >> 2) * 1024 + (g * 4 + (col & 3)) * 64 + d];
    }
    #pragma unroll
    for (int jj = 0; jj < 2; ++jj) {
        const int i2 = t + 256 * jj;    // < 512
        const int d = i2 & 63, vc = i2 >> 6;
        Bt[(64 + vc) * 68 + d] = Wor[((g * 4 + (vc >> 1)) * 64 + d) * 2 + (vc & 1)];
    }
    {
        const int i = t >> 4, dc = (t & 15) * 4;
        *(float4*)&As[i * 68 + dc] = *(const float4*)(Wk + (size_t)(i0 + i) * 256 + g * 64 + dc);
    }
    __syncthreads();
    const int jc = t & 63, iq = t >> 6;
    {
        float o4[4] = {0.f, 0.f, 0.f, 0.f};
        #pragma unroll
        for (int dc = 0; dc < 16; ++dc) {
            const float4 bv = *(const float4*)&Bt[jc * 68 + dc * 4];
            #pragma unroll
            for (int r = 0; r < 4; ++r) {
                const float4 av = *(const float4*)&As[(iq * 4 + r) * 68 + dc * 4];
                o4[r] = fmaf(av.x, bv.x, o4[r]);
                o4[r] = fmaf(av.y, bv.y, o4[r]);
                o4[r] = fmaf(av.z, bv.z, o4[r]);
                o4[r] = fmaf(av.w, bv.w, o4[r]);
            }
        }
        const int j = (jc >> 2) * 16 + g * 4 + (jc & 3);
        #pragma unroll
        for (int r = 0; r < 4; ++r) {
            unsigned short hh, ll;
            split_bf16(o4[r] * 0.125f, hh, ll);   // 1/sqrt(HD) folded in
            Wth[(size_t)j * 1024 + i0 + iq * 4 + r] = hh;
            Wtl[(size_t)j * 1024 + i0 + iq * 4 + r] = ll;
        }
    }
    __syncthreads();
    {
        const int i = t >> 4, dc = (t & 15) * 4;
        *(float4*)&As[i * 68 + dc] = *(const float4*)(Wv + (size_t)(i0 + i) * 256 + g * 64 + dc);
    }
    __syncthreads();
    if (t < 128) {
        const int il = t >> 3, vc = t & 7;
        float acc = 0.f;
        #pragma unroll
        for (int dc = 0; dc < 16; ++dc) {
            const float4 av = *(const float4*)&As[il * 68 + dc * 4];
            const float4 bv = *(const float4*)&Bt[(64 + vc) * 68 + dc * 4];
            acc = fmaf(av.x, bv.x, acc);
            acc = fmaf(av.y, bv.y, acc);
            acc = fmaf(av.z, bv.z, acc);
            acc = fmaf(av.w, bv.w, acc);
        }
        const int j = 256 + (g * 4 + (vc >> 1)) * 2 + (vc & 1);
        unsigned short hh, ll;
        split_bf16(acc, hh, ll);
        Wth[(size_t)j * 1024 + i0 + il] = hh;
        Wtl[(size_t)j * 1024 + i0 + il] = ll;
    }
}

// ------- k2: pure-bf16 MFMA GEMM, tile 64x64, BK=64, K-split 2, reg prefetch -------
__global__ __launch_bounds__(256) void k2(
    const unsigned short* __restrict__ Ahg, const unsigned short* __restrict__ Alg,
    const unsigned short* __restrict__ Wth, const unsigned short* __restrict__ Wtl,
    float* __restrict__ S0, float* __restrict__ S1,
    float* __restrict__ VW0, float* __restrict__ VW1)
{
    __shared__ unsigned short Ah[64 * 72], Al[64 * 72];   // [m][k], stride 72 shorts
    __shared__ unsigned short Bh[64 * 72], Bl[64 * 72];   // [n][k]   (36 KB total)
    const int m0 = blockIdx.x * 64;
    const int n0 = blockIdx.y * 64;
    const int kh = blockIdx.z;
    const int t = threadIdx.x;
    const int lane = t & 63, wv = t >> 6;
    const int l16 = lane & 15, quad = lane >> 4;
    const int wm = wv >> 1, wn = wv & 1;
    const int sr = t >> 2, kc = (t & 3) * 8;
    v4f acc[2][2];
    #pragma unroll
    for (int i = 0; i < 2; ++i)
        #pragma unroll
        for (int j = 0; j < 2; ++j) acc[i][j] = (v4f)(0.f);
    const unsigned short* Aph = Ahg + (size_t)(m0 + sr) * 1024 + kh * 512 + kc;
    const unsigned short* Apl = Alg + (size_t)(m0 + sr) * 1024 + kh * 512 + kc;
    const unsigned short* Bph = Wth + (size_t)(n0 + sr) * 1024 + kh * 512 + kc;
    const unsigned short* Bpl = Wtl + (size_t)(n0 + sr) * 1024 + kh * 512 + kc;
    // prefetch iter 0 staging regs
    v8s rah0 = *(const v8s*)(Aph);      v8s rah1 = *(const v8s*)(Aph + 32);
    v8s ral0 = *(const v8s*)(Apl);      v8s ral1 = *(const v8s*)(Apl + 32);
    v8s rbh0 = *(const v8s*)(Bph);      v8s rbh1 = *(const v8s*)(Bph + 32);
    v8s rbl0 = *(const v8s*)(Bpl);      v8s rbl1 = *(const v8s*)(Bpl + 32);
    for (int k0 = 0; k0 < 512; k0 += 64) {
        __syncthreads();
        *(v8s*)&Ah[sr * 72 + kc] = rah0;  *(v8s*)&Ah[sr * 72 + kc + 32] = rah1;
        *(v8s*)&Al[sr * 72 + kc] = ral0;  *(v8s*)&Al[sr * 72 + kc + 32] = ral1;
        *(v8s*)&Bh[sr * 72 + kc] = rbh0;  *(v8s*)&Bh[sr * 72 + kc + 32] = rbh1;
        *(v8s*)&Bl[sr * 72 + kc] = rbl0;  *(v8s*)&Bl[sr * 72 + kc + 32] = rbl1;
        __syncthreads();
        if (k0 + 64 < 512) {   // issue next-iter loads under the MFMA section
            const int kn = k0 + 64;
            rah0 = *(const v8s*)(Aph + kn);  rah1 = *(const v8s*)(Aph + kn + 32);
            ral0 = *(const v8s*)(Apl + kn);  ral1 = *(const v8s*)(Apl + kn + 32);
            rbh0 = *(const v8s*)(Bph + kn);  rbh1 = *(const v8s*)(Bph + kn + 32);
            rbl0 = *(const v8s*)(Bpl + kn);  rbl1 = *(const v8s*)(Bpl + kn + 32);
        }
        #pragma unroll
        for (int kk = 0; kk < 2; ++kk) {
            v8s fah[2], fal[2], fbh[2], fbl[2];
            #pragma unroll
            for (int s = 0; s < 2; ++s) {
                const int mr = wm * 32 + s * 16 + l16;
                fah[s] = *(const v8s*)&Ah[mr * 72 + kk * 32 + quad * 8];
                fal[s] = *(const v8s*)&Al[mr * 72 + kk * 32 + quad * 8];
                const int nr = wn * 32 + s * 16 + l16;
                fbh[s] = *(const v8s*)&Bh[nr * 72 + kk * 32 + quad * 8];
                fbl[s] = *(const v8s*)&Bl[nr * 72 + kk * 32 + quad * 8];
            }
            #pragma unroll
            for (int ms = 0; ms < 2; ++ms)
                #pragma unroll
                for (int ns = 0; ns < 2; ++ns) {
                    acc[ms][ns] = __builtin_amdgcn_mfma_f32_16x16x32_bf16(fal[ms], fbh[ns], acc[ms][ns], 0, 0, 0);
                    acc[ms][ns] = __builtin_amdgcn_mfma_f32_16x16x32_bf16(fah[ms], fbl[ns], acc[ms][ns], 0, 0, 0);
                    acc[ms][ns] = __builtin_amdgcn_mfma_f32_16x16x32_bf16(fah[ms], fbh[ns], acc[ms][ns], 0, 0, 0);
                }
        }
    }
    float* Sh  = kh ? S1 : S0;
    float* VWh = kh ? VW1 : VW0;
    #pragma unroll
    for (int ms = 0; ms < 2; ++ms)
        #pragma unroll
        for (int ns = 0; ns < 2; ++ns) {
            const int j = n0 + wn * 32 + ns * 16 + l16;
            if (j >= 288) continue;
            const int m = m0 + wm * 32 + ms * 16 + quad * 4;   // C/D: col=lane&15, row=quad*4+reg
            const int bb = m >> 9, tt = m & 511;
            const float4 v = make_float4(acc[ms][ns][0], acc[ms][ns][1], acc[ms][ns][2], acc[ms][ns][3]);
            float* dst;
            if (j < 256)
                dst = Sh + (size_t)((bb * 16 + (j >> 4)) * 16 + (j & 15)) * SROW + 32 + tt;
            else
                dst = VWh + (size_t)(bb * 32 + (j - 256)) * SROW + 32 + tt;
            *(float4*)dst = v;
        }
}

// ---------------- k3: exp + sliding-window softmax + head-reduce (quarter-m) -------
__global__ __launch_bounds__(256) void k3(
    const float* __restrict__ S0, const float* __restrict__ S1,
    const float* __restrict__ VW0, const float* __restrict__ VW1,
    const float* __restrict__ brp, float* __restrict__ out)
{
    __shared__ float Es[16 * 164];
    __shared__ float EVs[32 * 164];
    const int b = blockIdx.x, q = blockIdx.y, qt = blockIdx.z;
    const int tbase = qt * 128;
    const int t = threadIdx.x;
    for (int idx = t; idx < 640; idx += 256) {          // 16 h x 40 float4 (wi<160)
        const int h = idx / 40, g = idx - h * 40;
        const size_t off = (size_t)((b * 16 + q) * 16 + h) * SROW + tbase + g * 4;
        const float4 a = *(const float4*)(S0 + off);
        const float4 c = *(const float4*)(S1 + off);
        float4 e;
        e.x = __expf(a.x + c.x); e.y = __expf(a.y + c.y);
        e.z = __expf(a.z + c.z); e.w = __expf(a.w + c.w);
        *(float4*)(Es + h * 164 + g * 4) = e;
    }
    __syncthreads();
    for (int idx = t; idx < 1280; idx += 256) {         // 32 hc x 40 float4
        const int hc = idx / 40, g = idx - hc * 40;
        const size_t off = (size_t)(b * 32 + hc) * SROW + tbase + g * 4;
        const float4 v0 = *(const float4*)(VW0 + off);
        const float4 v1 = *(const float4*)(VW1 + off);
        const float4 e = *(const float4*)(Es + (hc >> 1) * 164 + g * 4);
        float4 rr;
        rr.x = e.x * (v0.x + v1.x); rr.y = e.y * (v0.y + v1.y);
        rr.z = e.z * (v0.z + v1.z); rr.w = e.w * (v0.w + v1.w);
        *(float4*)(EVs + hc * 164 + g * 4) = rr;
    }
    __syncthreads();
    const int h = t & 15, mg = t >> 4;
    const float* ep = Es + h * 164 + mg * 8;
    const float* e0 = EVs + (2 * h) * 164 + mg * 8;
    const float* e1 = EVs + (2 * h + 1) * 164 + mg * 8;
    float den = 0.f, n0s = 0.f, n1s = 0.f;
    #pragma unroll
    for (int s = 0; s < 32; ++s) {
        const int ss = 1 + ((s + 2 * h) & 31);          // bank-rotated
        den += ep[ss]; n0s += e0[ss]; n1s += e1[ss];
    }
    const float br0 = brp[0], br1 = brp[1];
    #pragma unroll
    for (int u = 0; u < 8; ++u) {
        const float inv = __builtin_amdgcn_rcpf(den);
        float c0 = n0s * inv, c1 = n1s * inv;
        #pragma unroll
        for (int w = 1; w < 16; w <<= 1) {
            c0 += __shfl_xor(c0, w, 64);
            c1 += __shfl_xor(c1, w, 64);
        }
        if (h == 0) {
            const int m = tbase + mg * 8 + u;
            float* o = out + (size_t)((b * 512 + m) * 16 + q) * 2;
            o[0] = c0 + br0;
            o[1] = c1 + br1;
        }
        if (u < 7) {
            den += ep[33 + u] - ep[1 + u];
            n0s += e0[33 + u] - e0[1 + u];
            n1s += e1[33 + u] - e1[1 + u];
        }
    }
}

extern "C" void kernel_launch(void* const* d_in, const int* in_sizes, int n_in,
                              void* d_out, int out_size, void* d_ws, size_t ws_size,
                              hipStream_t stream)
{
    (void)in_sizes; (void)n_in; (void)out_size; (void)ws_size;
    const float* h  = (const float*)d_in[0];
    const float* fc = (const float*)d_in[1];
    const float* fs = (const float*)d_in[2];
    const float* Wq = (const float*)d_in[3];
    const float* Wk = (const float*)d_in[4];
    const float* Wv = (const float*)d_in[5];
    const float* Wo = (const float*)d_in[6];
    const float* oq = (const float*)d_in[7];
    const float* Wr = (const float*)d_in[8];
    const float* br = (const float*)d_in[9];
    float* ws = (float*)d_ws;
    float* Wor  = ws + OFF_WOR;
    float* qr   = ws + OFF_QR;
    unsigned short* Wth = (unsigned short*)(ws + OFF_WTH);
    unsigned short* Wtl = (unsigned short*)(ws + OFF_WTL);
    float* S0   = ws + OFF_S0;
    float* S1   = ws + OFF_S1;
    float* VW0  = ws + OFF_VW0;
    float* VW1  = ws + OFF_VW1;
    unsigned short* Ahg = (unsigned short*)(ws + OFF_AH);
    unsigned short* Alg = (unsigned short*)(ws + OFF_AL);
    float* out = (float*)d_out;

    hipLaunchKernelGGL(kP, dim3(2706), dim3(256), 0, stream,
                       oq, Wq, fc, fs, Wo, Wr, h, qr, Wor, S0, S1, VW0, VW1,
                       (unsigned*)Wth, (unsigned*)Wtl, Ahg, Alg);
    hipLaunchKernelGGL(kW, dim3(256), dim3(256), 0, stream, Wk, Wv, qr, Wor, Wth, Wtl);
    hipLaunchKernelGGL(k2, dim3(64, 5, 2), dim3(256), 0, stream, Ahg, Alg, Wth, Wtl, S0, S1, VW0, VW1);
    hipLaunchKernelGGL(k3, dim3(8, 16, 4), dim3(256), 0, stream, S0, S1, VW0, VW1, br, out);
}